// Round 12
// baseline (3942.326 us; speedup 1.0000x reference)
//
#include <hip/hip_runtime.h>
#include <hip/hip_bf16.h>

// Model dims
#define BN 64      // batch
#define TT 192     // total seq
#define ILEN 160   // input_len
#define DIN 8
#define DM 256
#define NH 8
#define DH 32
#define DFF 1024
#define NLAY 4
#define PRE_ROWS (BN * ILEN)   // 10240
#define SCALE 0.17677669529663687f  // 1/sqrt(32)
#define GROUP 8                // decode blocks per batch (1 head each; 2 blocks/CU)
#define CTR_STRIDE 64          // pad barrier counters to 256B each

typedef float f2v __attribute__((ext_vector_type(2)));
typedef _Float16 half8 __attribute__((ext_vector_type(8)));
typedef _Float16 h4v __attribute__((ext_vector_type(4)));
typedef float floatx4 __attribute__((ext_vector_type(4)));

#if defined(__has_builtin)
#if __has_builtin(__builtin_amdgcn_cvt_pk_f32_fp8) && __has_builtin(__builtin_amdgcn_cvt_pk_fp8_f32)
#define HW_FP8 1
#endif
#endif

// ---- software e4m3fn fallback (only used if builtins missing) ----
static __device__ inline float dec1_sw(unsigned b) {
    unsigned s = b >> 7, e = (b >> 3) & 15, mn = b & 7;
    float v;
    if (e == 0) v = (float)mn * 0.001953125f;
    else v = (8.0f + (float)mn) * exp2f((float)e - 10.0f);
    return s ? -v : v;
}
static __device__ inline unsigned enc1_sw(float x) {
    unsigned s = (x < 0.f) ? 0x80u : 0u;
    float ax = fabsf(x);
    if (ax > 448.f) ax = 448.f;
    if (ax < 0.0009765625f) return s;
    int e; frexpf(ax, &e);
    int E = e + 6;
    if (E <= 0) {
        int mn = (int)(ax * 512.f + 0.5f);
        if (mn > 7) return s | 0x08u;
        return s | (unsigned)mn;
    }
    if (E > 15) E = 15;
    int mn = (int)(ax * exp2f(10.f - (float)E) + 0.5f) - 8;
    if (mn > 7) { mn = 0; ++E; if (E > 15) { E = 15; mn = 7; } }
    if (mn < 0) mn = 0;
    return s | ((unsigned)E << 3) | (unsigned)mn;
}

static __device__ inline unsigned enc4(float a, float b, float c, float d) {
#ifdef HW_FP8
    int v = __builtin_amdgcn_cvt_pk_fp8_f32(a, b, 0, false);
    v = __builtin_amdgcn_cvt_pk_fp8_f32(c, d, v, true);
    return (unsigned)v;
#else
    return enc1_sw(a) | (enc1_sw(b) << 8) | (enc1_sw(c) << 16) | (enc1_sw(d) << 24);
#endif
}

static __device__ inline float dot4u(unsigned u, const float* h, float a) {
#ifdef HW_FP8
    f2v lo = __builtin_amdgcn_cvt_pk_f32_fp8((int)u, false);
    f2v hi = __builtin_amdgcn_cvt_pk_f32_fp8((int)u, true);
    a = fmaf(lo.x, h[0], a); a = fmaf(lo.y, h[1], a);
    a = fmaf(hi.x, h[2], a); a = fmaf(hi.y, h[3], a);
#else
    a = fmaf(dec1_sw(u & 255u), h[0], a);
    a = fmaf(dec1_sw((u >> 8) & 255u), h[1], a);
    a = fmaf(dec1_sw((u >> 16) & 255u), h[2], a);
    a = fmaf(dec1_sw((u >> 24) & 255u), h[3], a);
#endif
    return a;
}
static __device__ inline void dec4(unsigned u, float* o) {
#ifdef HW_FP8
    f2v lo = __builtin_amdgcn_cvt_pk_f32_fp8((int)u, false);
    f2v hi = __builtin_amdgcn_cvt_pk_f32_fp8((int)u, true);
    o[0] = lo.x; o[1] = lo.y; o[2] = hi.x; o[3] = hi.y;
#else
    o[0] = dec1_sw(u & 255u); o[1] = dec1_sw((u >> 8) & 255u);
    o[2] = dec1_sw((u >> 16) & 255u); o[3] = dec1_sw((u >> 24) & 255u);
#endif
}

// ---------------- copy whole_example -> out ----------------
__global__ void copy_out_k(const float* __restrict__ X, float* __restrict__ O, int n) {
    int i = blockIdx.x * blockDim.x + threadIdx.x;
    if (i < n) O[i] = X[i];
}

// ---------------- zero the (padded) group-barrier counters ----------------
__global__ void init_ctr_k(unsigned* __restrict__ ctr) {
    int i = blockIdx.x * 256 + threadIdx.x;
    if (i < BN * CTR_STRIDE) ctr[i] = 0u;
}

// ---------------- pack fp32 [K][N] -> fp8 dwords [K/4][N], x256; z = layer ----------------
__global__ __launch_bounds__(256) void pack8_k(const float* __restrict__ src0,
        unsigned* __restrict__ dst0, int N, size_t sstride, size_t dstride) {
    const float* src = src0 + blockIdx.z * sstride;
    unsigned* dst = dst0 + blockIdx.z * dstride;
    int o = blockIdx.x * 256 + threadIdx.x;
    int k4 = blockIdx.y;
    if (o < N) {
        float a = src[(size_t)(4 * k4) * N + o] * 256.f;
        float b = src[(size_t)(4 * k4 + 1) * N + o] * 256.f;
        float c = src[(size_t)(4 * k4 + 2) * N + o] * 256.f;
        float d = src[(size_t)(4 * k4 + 3) * N + o] * 256.f;
        dst[(size_t)k4 * N + o] = enc4(a, b, c, d);
    }
}

// ---------------- pack fp32 [K][N] -> f16 MFMA B-fragments (prefill); y = layer ----------------
__global__ __launch_bounds__(256) void packBf_k(const float* __restrict__ W,
        half8* __restrict__ dst, int N, int K, size_t wstride, size_t dstride) {
    const float* Wl = W + blockIdx.y * wstride;
    half8* dl = dst + blockIdx.y * dstride;
    int idx = blockIdx.x * 256 + threadIdx.x;
    int l = idx & 63;
    int f = idx >> 6;
    int nfr = N >> 4;
    if (f < (K >> 5) * nfr) {
        int ktg = f / nfr, ctg = f - ktg * nfr;
        int row = ktg * 32 + 8 * (l >> 4);
        int col = ctg * 16 + (l & 15);
        half8 v;
#pragma unroll
        for (int i = 0; i < 8; ++i)
            v[i] = (_Float16)Wl[(size_t)(row + i) * N + col];
        dl[(size_t)f * 64 + l] = v;
    }
}

// ---------------- embedding for prefill rows ----------------
__global__ __launch_bounds__(256) void embed_k(const float* __restrict__ X,
        const float* __restrict__ w, const float* __restrict__ bias,
        float* __restrict__ H) {
    int row = blockIdx.x;
    int b = row / ILEN, p = row % ILEN;
    int tid = threadIdx.x;
    const float* x = X + (size_t)(b * TT + p) * DIN;
    float acc = bias[tid];
#pragma unroll
    for (int r = 0; r < DIN; ++r) acc += x[r] * w[r * DM + tid];
    H[(size_t)row * DM + tid] = acc;
}

// ---- shared A-staging: 64 rows x 256 cols f32 -> f16 LDS, fully coalesced ----
static __device__ inline void stageA(const float* __restrict__ A, int row0, int K,
                                     int kc0, _Float16 (*As)[264], int tid) {
#pragma unroll
    for (int i = 0; i < 16; ++i) {
        int idx = i * 256 + tid;            // 0..4095
        int r = idx >> 6, c4 = (idx & 63) * 4;
        float4 v = *(const float4*)(A + (size_t)(row0 + r) * K + kc0 + c4);
        h4v hv = {(_Float16)v.x, (_Float16)v.y, (_Float16)v.z, (_Float16)v.w};
        *(h4v*)&As[r][c4] = hv;
    }
}

// ---------------- MFMA f16 GEMM: C = A@W + bias (+epilogue) ----------------
__global__ __launch_bounds__(256) void mgemm_k(
        const float* __restrict__ A, const half8* __restrict__ Bp,
        const float* __restrict__ bias, const float* __restrict__ R,
        float* __restrict__ C, int N, int K, int mode, int remap) {
    __shared__ _Float16 As[64][264];
    const int tid = threadIdx.x;
    const int lane = tid & 63;
    const int w16 = (tid >> 6) * 16;
    const int bx = blockIdx.x;
    const int row0 = blockIdx.y * 64;
    const int nfr = N >> 4;
    const int ctg0 = bx << 2;

    floatx4 acc[4] = {};
    for (int kc0 = 0; kc0 < K; kc0 += 256) {
        stageA(A, row0, K, kc0, As, tid);
        __syncthreads();
#pragma unroll
        for (int kt = 0; kt < 8; ++kt) {
            half8 af = *(const half8*)&As[w16 + (lane & 15)][kt * 32 + 8 * (lane >> 4)];
            size_t ktg = (kc0 >> 5) + kt;
#pragma unroll
            for (int ct = 0; ct < 4; ++ct) {
                half8 bf = Bp[(ktg * nfr + ctg0 + ct) * 64 + lane];
                acc[ct] = __builtin_amdgcn_mfma_f32_16x16x32_f16(af, bf, acc[ct], 0, 0, 0);
            }
        }
        __syncthreads();
    }
    int rbase = row0 + w16 + 4 * (lane >> 4);
#pragma unroll
    for (int ct = 0; ct < 4; ++ct) {
        int col = (bx << 6) + (ct << 4) + (lane & 15);
        float bb = bias[col];
#pragma unroll
        for (int i = 0; i < 4; ++i) {
            int row = rbase + i;
            float v = acc[ct][i] + bb;
            if (mode == 1) v = fmaxf(v, 0.f);
            if (mode == 2) v += R[(size_t)row * N + col];
            int orow = remap ? (row / ILEN) * TT + (row % ILEN) : row;
            C[(size_t)orow * N + col] = v;
        }
    }
}

// ---------------- fused QKV MFMA GEMM (K=256, N=256 each; mat by blockIdx.x>>2) ----------------
__global__ __launch_bounds__(256) void mgemm_qkv_k(
        const float* __restrict__ A,
        const half8* __restrict__ qf, const half8* __restrict__ kf,
        const half8* __restrict__ vf,
        const float* __restrict__ bq, const float* __restrict__ bk,
        const float* __restrict__ bv,
        float* __restrict__ qa, float* __restrict__ Kc, float* __restrict__ Vc) {
    __shared__ _Float16 As[64][264];
    const int tid = threadIdx.x;
    const int lane = tid & 63;
    const int w16 = (tid >> 6) * 16;
    const int mat = blockIdx.x >> 2;
    const int bx = blockIdx.x & 3;
    const int row0 = blockIdx.y * 64;
    const int ctg0 = bx << 2;
    const half8* Bp = (mat == 0) ? qf : (mat == 1) ? kf : vf;
    const float* bias = (mat == 0) ? bq : (mat == 1) ? bk : bv;
    float* C = (mat == 0) ? qa : (mat == 1) ? Kc : Vc;

    floatx4 acc[4] = {};
    stageA(A, row0, DM, 0, As, tid);
    __syncthreads();
#pragma unroll
    for (int kt = 0; kt < 8; ++kt) {
        half8 af = *(const half8*)&As[w16 + (lane & 15)][kt * 32 + 8 * (lane >> 4)];
#pragma unroll
        for (int ct = 0; ct < 4; ++ct) {
            half8 bf = Bp[((size_t)kt * 16 + ctg0 + ct) * 64 + lane];
            acc[ct] = __builtin_amdgcn_mfma_f32_16x16x32_f16(af, bf, acc[ct], 0, 0, 0);
        }
    }
    int rbase = row0 + w16 + 4 * (lane >> 4);
#pragma unroll
    for (int ct = 0; ct < 4; ++ct) {
        int col = (bx << 6) + (ct << 4) + (lane & 15);
        float bb = bias[col];
#pragma unroll
        for (int i = 0; i < 4; ++i) {
            int row = rbase + i;
            float v = acc[ct][i] + bb;
            int orow = mat ? (row / ILEN) * TT + (row % ILEN) : row;
            C[(size_t)orow * DM + col] = v;
        }
    }
}

// ---------------- prefill attention (coalesced K-dot) ----------------
__global__ __launch_bounds__(256) void attn_k(
        const float* __restrict__ Q, const float* __restrict__ Kc,
        const float* __restrict__ Vc, float* __restrict__ O) {
    int qp = blockIdx.x;
    int b = blockIdx.y;
    int tid = threadIdx.x;
    int hh = tid >> 5, l = tid & 31;
    int jj = l >> 3, dd = l & 7;      // 4 j-rows x 8 d-quads per 32-lane group
    __shared__ float qs[DM];
    __shared__ float sc[NH][TT];
    int qrow = b * ILEN + qp;
    qs[tid] = Q[(size_t)qrow * DM + tid] * SCALE;
    __syncthreads();
    const float* Kb = Kc + (size_t)b * TT * DM;
    const float* Vb = Vc + (size_t)b * TT * DM;
    float q0 = qs[hh * DH + dd * 4], q1 = qs[hh * DH + dd * 4 + 1];
    float q2 = qs[hh * DH + dd * 4 + 2], q3 = qs[hh * DH + dd * 4 + 3];
    float mx = -1e30f;
    for (int jb = 0; jb <= qp; jb += 4) {
        int j = jb + jj;
        bool ok = (j <= qp);
        int jc = ok ? j : qp;
        float4 kv = *(const float4*)(Kb + (size_t)jc * DM + hh * DH + dd * 4);
        float pd = kv.x * q0 + kv.y * q1 + kv.z * q2 + kv.w * q3;
        pd += __shfl_xor(pd, 1); pd += __shfl_xor(pd, 2); pd += __shfl_xor(pd, 4);
        if (ok) {
            if (dd == 0) sc[hh][j] = pd;
            mx = fmaxf(mx, pd);
        }
    }
#pragma unroll
    for (int o = 16; o > 0; o >>= 1) mx = fmaxf(mx, __shfl_xor(mx, o, 32));
    float sum = 0.f;
    for (int j = l; j <= qp; j += 32) {
        float p = __expf(sc[hh][j] - mx);
        sc[hh][j] = p;
        sum += p;
    }
#pragma unroll
    for (int o = 16; o > 0; o >>= 1) sum += __shfl_xor(sum, o, 32);
    float inv = 1.f / sum;
    float acc = 0.f;
    for (int j = 0; j <= qp; ++j)
        acc += sc[hh][j] * Vb[(size_t)j * DM + hh * DH + l];
    O[(size_t)qrow * DM + hh * DH + l] = acc * inv;
}

// ---------------- layernorm: one wave per row, 4 rows/block ----------------
__global__ __launch_bounds__(256) void ln4_k(const float* __restrict__ Xp,
        const float* __restrict__ g, const float* __restrict__ be,
        float* __restrict__ Y) {
    int row = blockIdx.x * 4 + (threadIdx.x >> 6);
    int l = threadIdx.x & 63;
    float4 x = *(const float4*)(Xp + (size_t)row * DM + 4 * l);
    float s = x.x + x.y + x.z + x.w;
    float s2 = x.x * x.x + x.y * x.y + x.z * x.z + x.w * x.w;
#pragma unroll
    for (int o = 32; o > 0; o >>= 1) { s += __shfl_xor(s, o); s2 += __shfl_xor(s2, o); }
    float mu = s * (1.f / 256.f);
    float var = s2 * (1.f / 256.f) - mu * mu;
    float rr = rsqrtf(var + 1e-5f);
    float4 gv = *(const float4*)(g + 4 * l);
    float4 bv = *(const float4*)(be + 4 * l);
    float4 o;
    o.x = (x.x - mu) * rr * gv.x + bv.x;
    o.y = (x.y - mu) * rr * gv.y + bv.y;
    o.z = (x.z - mu) * rr * gv.z + bv.z;
    o.w = (x.w - mu) * rr * gv.w + bv.w;
    *(float4*)(Y + (size_t)row * DM + 4 * l) = o;
}

// ---------------- final projection at position 159 -> pred0 ----------------
__global__ __launch_bounds__(256) void final_k(const float* __restrict__ H,
        const float* __restrict__ fw, const float* __restrict__ fb,
        float* __restrict__ out) {
    int b = blockIdx.x;
    int tid = threadIdx.x;
    float v = H[(size_t)(b * ILEN + ILEN - 1) * DM + tid] * fw[tid];
#pragma unroll
    for (int o = 32; o > 0; o >>= 1) v += __shfl_xor(v, o);
    __shared__ float red[4];
    if ((tid & 63) == 0) red[tid >> 6] = v;
    __syncthreads();
    if (tid == 0)
        out[((size_t)b * TT + ILEN) * DIN] = red[0] + red[1] + red[2] + red[3] + fb[0];
}

// ================= decode v10: 8 members/batch (1 head each), 2 blocks/CU ========
__device__ inline void gbar(unsigned* __restrict__ c, unsigned target, int tid) {
    __syncthreads();
    if (tid == 0) {
        __hip_atomic_fetch_add(c, 1u, __ATOMIC_RELAXED, __HIP_MEMORY_SCOPE_AGENT);
        int guard = 0;
        while (__hip_atomic_load(c, __ATOMIC_RELAXED, __HIP_MEMORY_SCOPE_AGENT) < target) {
            __builtin_amdgcn_s_sleep(1);
            if (++guard > (1 << 27)) break;
        }
    }
    __syncthreads();
}

#define KSTRIDE 12   // dwords/row (8 used), 48B rows -> 16B-aligned uint4 reads
#define VSTRIDE 9    // dwords/row (8 used), odd -> bank spread on dword reads

__global__ __launch_bounds__(1024, 8) void decode10_k(
        const float* __restrict__ X,
        const float* __restrict__ emb_w, const float* __restrict__ emb_b,
        const float* __restrict__ bq, const float* __restrict__ bk,
        const float* __restrict__ bv, const float* __restrict__ bo,
        const float* __restrict__ ln1g, const float* __restrict__ ln1b,
        const float* __restrict__ b1, const float* __restrict__ b2,
        const float* __restrict__ ln2g, const float* __restrict__ ln2b,
        const float* __restrict__ fw, const float* __restrict__ fb,
        const float* __restrict__ Kc, const float* __restrict__ Vc,
        const unsigned* __restrict__ qp8, const unsigned* __restrict__ kp8,
        const unsigned* __restrict__ vp8, const unsigned* __restrict__ op8,
        const unsigned* __restrict__ w18, const unsigned* __restrict__ w28,
        float* __restrict__ opart, float* __restrict__ f2part,
        unsigned* __restrict__ ctrs,
        float* __restrict__ out) {
    const int bid = blockIdx.x;
    const int b = bid & 63;        // batch
    const int m = bid >> 6;        // member 0..7 = head index (bid%8 == b%8: same XCD)
    const int tid = threadIdx.x;
    const int wid = tid >> 6;
    unsigned* ctr = ctrs + b * CTR_STRIDE;
    unsigned bt = 0;

    __shared__ unsigned Kl[NLAY * 192 * KSTRIDE];   // 36.9 KB  my head's K (8 dw/row)
    __shared__ unsigned Vl[NLAY * 192 * VSTRIDE];   // 27.6 KB  my head's V
    __shared__ float hs[256];
    __shared__ float qs[32];
    __shared__ float as_[32];
    __shared__ float sc[192];
    __shared__ float scr[1100];
    __shared__ float tmp[128];
    __shared__ float ffs[128];
    __shared__ float red[16], red2[16];

    // ---- seed prefill KV rows 0..159 into LDS (fp8, x64): 4L x 160 x 8d4 = 5120 ----
    for (int it = 0; it < 5; ++it) {
        int idx = it * 1024 + tid;
        int d4 = idx & 7;
        int r640 = idx >> 3;
        int l = r640 / 160;
        int row = r640 - l * 160;
        size_t base = ((size_t)(l * BN + b) * TT + row) * DM + m * 32 + d4 * 4;
        float4 kf = *(const float4*)(Kc + base);
        float4 vf = *(const float4*)(Vc + base);
        Kl[(l * 192 + row) * KSTRIDE + d4] =
            enc4(kf.x * 64.f, kf.y * 64.f, kf.z * 64.f, kf.w * 64.f);
        Vl[(l * 192 + row) * VSTRIDE + d4] =
            enc4(vf.x * 64.f, vf.y * 64.f, vf.z * 64.f, vf.w * 64.f);
    }
    float pred = out[((size_t)b * TT + ILEN) * DIN];
    __syncthreads();

    for (int t = 0; t < TT - ILEN - 1; ++t) {   // 31 steps
        const int p = ILEN + t;
        __syncthreads();
        if (tid < 256) {
            float a = emb_b[tid];
#pragma unroll
            for (int r = 0; r < DIN; ++r) {
                float xr = (r == 0) ? pred : X[((size_t)b * TT + p) * DIN + r];
                a += xr * emb_w[r * DM + tid];
            }
            hs[tid] = a;
        }
        __syncthreads();

        for (int li = 0; li < NLAY; ++li) {
            const unsigned* wq8 = qp8 + (size_t)li * 16384;
            const unsigned* wk8 = kp8 + (size_t)li * 16384;
            const unsigned* wv8 = vp8 + (size_t)li * 16384;
            const unsigned* wo8 = op8 + (size_t)li * 16384;
            const unsigned* w18l = w18 + (size_t)li * 65536;
            const unsigned* w28l = w28 + (size_t)li * 65536;

            // ---- A: QKV for my 32 dims; (mat,kc in 8, o in 32); 8 loads/thread ----
            if (tid < 768) {
                int mat = tid >> 8, r = tid & 255, o = r & 31, kc = r >> 5;
                int og = m * 32 + o;
                const unsigned* w = (mat == 0) ? wq8 : (mat == 1) ? wk8 : wv8;
                const unsigned* wp = w + (size_t)(kc * 8) * 256 + og;
                const float* hq = hs + kc * 32;
                float a = 0.f;
#pragma unroll
                for (int i = 0; i < 8; ++i)
                    a = dot4u(wp[(size_t)i * 256], hq + i * 4, a);
                scr[mat * 256 + kc * 32 + o] = a;
            }
            __syncthreads();
            if (tid < 96) {
                int mat = tid >> 5, o = tid & 31, og = m * 32 + o;
                float v = 0.f;
#pragma unroll
                for (int kc = 0; kc < 8; ++kc) v += scr[mat * 256 + kc * 32 + o];
                v *= (1.f / 256.f);
                if (mat == 0) qs[o] = (v + bq[li * DM + og]) * (SCALE / 64.f);
                else if (mat == 1) tmp[o] = (v + bk[li * DM + og]) * 64.f;
                else tmp[32 + o] = (v + bv[li * DM + og]) * 64.f;
            }
            __syncthreads();
            if (tid < 16) {
                int i = tid & 7;
                if (tid < 8)
                    Kl[(li * 192 + p) * KSTRIDE + i] =
                        enc4(tmp[4 * i], tmp[4 * i + 1], tmp[4 * i + 2], tmp[4 * i + 3]);
                else
                    Vl[(li * 192 + p) * VSTRIDE + i] =
                        enc4(tmp[32 + 4 * i], tmp[32 + 4 * i + 1],
                             tmp[32 + 4 * i + 2], tmp[32 + 4 * i + 3]);
            }
            __syncthreads();

            // ---- B: attention for my single head, all in LDS ----
            {
                const int u = tid;
                float mval = -1e30f;
                if (u <= p) {
                    const unsigned* kr = Kl + (li * 192 + u) * KSTRIDE;
                    uint4 k0 = *(const uint4*)kr;
                    uint4 k1 = *(const uint4*)(kr + 4);
                    float d = 0.f;
                    d = dot4u(k0.x, qs + 0, d);  d = dot4u(k0.y, qs + 4, d);
                    d = dot4u(k0.z, qs + 8, d);  d = dot4u(k0.w, qs + 12, d);
                    d = dot4u(k1.x, qs + 16, d); d = dot4u(k1.y, qs + 20, d);
                    d = dot4u(k1.z, qs + 24, d); d = dot4u(k1.w, qs + 28, d);
                    sc[u] = d;
                    mval = d;
                }
#pragma unroll
                for (int o = 32; o > 0; o >>= 1) mval = fmaxf(mval, __shfl_xor(mval, o));
                if ((tid & 63) == 0) red[wid] = mval;
                __syncthreads();
                float mx = red[0];
#pragma unroll
                for (int r = 1; r < 16; ++r) mx = fmaxf(mx, red[r]);
                float sval = 0.f;
                if (u <= p) {
                    float e = __expf(sc[u] - mx);
                    sc[u] = e;
                    sval = e;
                }
#pragma unroll
                for (int o = 32; o > 0; o >>= 1) sval += __shfl_xor(sval, o);
                if ((tid & 63) == 0) red2[wid] = sval;
                __syncthreads();
                // PV: (d4 in 8, jc in 32); 6 fixed iters
                if (tid < 256) {
                    int d4 = tid & 7, jc = tid >> 3;
                    float a0 = 0.f, a1 = 0.f, a2 = 0.f, a3 = 0.f;
#pragma unroll
                    for (int it2 = 0; it2 < 6; ++it2) {
                        int j = jc + 32 * it2;
                        if (j <= p) {
                            float pe = sc[j];
                            float vv[4];
                            dec4(Vl[(li * 192 + j) * VSTRIDE + d4], vv);
                            a0 = fmaf(pe, vv[0], a0); a1 = fmaf(pe, vv[1], a1);
                            a2 = fmaf(pe, vv[2], a2); a3 = fmaf(pe, vv[3], a3);
                        }
                    }
                    int ob = d4 * 4;
                    scr[(ob + 0) * 33 + jc] = a0; scr[(ob + 1) * 33 + jc] = a1;
                    scr[(ob + 2) * 33 + jc] = a2; scr[(ob + 3) * 33 + jc] = a3;
                }
            }
            __syncthreads();
            if (tid < 128) {
                int o = tid & 31, q4 = tid >> 5;
                float a = 0.f;
#pragma unroll
                for (int r = 0; r < 8; ++r) a += scr[o * 33 + q4 * 8 + r];
                tmp[q4 * 32 + o] = a;
            }
            __syncthreads();
            if (tid < 32) {
                float s = red2[0];
#pragma unroll
                for (int r = 1; r < 16; ++r) s += red2[r];
                float inv = 1.f / (64.f * s);
                as_[tid] = (tmp[tid] + tmp[32 + tid] + tmp[64 + tid] + tmp[96 + tid]) * inv;
            }
            __syncthreads();

            // ---- C: O-projection partial (my 32 attn dims x 256 outs); 2 loads/thread ----
            {
                int o = tid & 255, kc = tid >> 8;
                const unsigned* wp = wo8 + (size_t)(m * 8 + kc * 2) * 256 + o;
                const float* aq = as_ + kc * 8;
                float a = 0.f;
                a = dot4u(wp[0], aq, a);
                a = dot4u(wp[256], aq + 4, a);
                scr[kc * 256 + o] = a;
            }
            __syncthreads();
            if (tid < 256)
                __hip_atomic_store(&opart[((size_t)b * GROUP + m) * DM + tid],
                    (scr[tid] + scr[256 + tid] + scr[512 + tid] + scr[768 + tid]) * (1.f / 256.f),
                    __ATOMIC_RELAXED, __HIP_MEMORY_SCOPE_AGENT);
            bt += GROUP; gbar(ctr, bt, tid);

            // ---- D: residual + LN1 (redundant) ----
            {
                float x = 0.f;
                if (tid < 256) {
                    x = hs[tid] + bo[li * DM + tid];
                    const float* opb = opart + (size_t)b * GROUP * DM + tid;
#pragma unroll
                    for (int mm = 0; mm < GROUP; ++mm)
                        x += __hip_atomic_load(&opb[mm * DM], __ATOMIC_RELAXED,
                                               __HIP_MEMORY_SCOPE_AGENT);
                }
                float s = x, s2 = x * x;
#pragma unroll
                for (int o = 32; o > 0; o >>= 1) { s += __shfl_xor(s, o); s2 += __shfl_xor(s2, o); }
                if ((tid & 63) == 0) { red[wid] = s; red2[wid] = s2; }
                __syncthreads();
                if (tid < 256) {
                    float S = red[0] + red[1] + red[2] + red[3];
                    float S2 = red2[0] + red2[1] + red2[2] + red2[3];
                    float mu = S * (1.f / 256.f);
                    float var = S2 * (1.f / 256.f) - mu * mu;
                    float rr = rsqrtf(var + 1e-5f);
                    hs[tid] = (x - mu) * rr * ln1g[li * DM + tid] + ln1b[li * DM + tid];
                }
                __syncthreads();
            }
            // ---- E: FFN1 (+relu), my 128 outs; (o in 128, kc in 8); 8 loads ----
            {
                int o = tid & 127, kc = tid >> 7;
                const unsigned* wp = w18l + (size_t)(kc * 8) * 1024 + m * 128 + o;
                const float* hq = hs + kc * 32;
                float a = 0.f;
#pragma unroll
                for (int i = 0; i < 8; ++i)
                    a = dot4u(wp[(size_t)i * 1024], hq + i * 4, a);
                scr[kc * 128 + o] = a;
            }
            __syncthreads();
            if (tid < 128) {
                float v = 0.f;
#pragma unroll
                for (int kc = 0; kc < 8; ++kc) v += scr[kc * 128 + tid];
                ffs[tid] = fmaxf(v * (1.f / 256.f) + b1[li * DFF + m * 128 + tid], 0.f);
            }
            __syncthreads();
            // ---- F: FFN2 partial over my own ff slice; (o in 256, kc in 4); 8 loads ----
            {
                int o = tid & 255, kc = tid >> 8;
                const unsigned* wp = w28l + (size_t)(m * 32 + kc * 8) * 256 + o;
                const float* hq = ffs + kc * 32;
                float a = 0.f;
#pragma unroll
                for (int i = 0; i < 8; ++i)
                    a = dot4u(wp[(size_t)i * 256], hq + i * 4, a);
                scr[kc * 256 + o] = a;
            }
            __syncthreads();
            if (tid < 256)
                __hip_atomic_store(&f2part[((size_t)b * GROUP + m) * DM + tid],
                    (scr[tid] + scr[256 + tid] + scr[512 + tid] + scr[768 + tid]) * (1.f / 256.f),
                    __ATOMIC_RELAXED, __HIP_MEMORY_SCOPE_AGENT);
            bt += GROUP; gbar(ctr, bt, tid);

            // ---- G: residual + LN2 (redundant) ----
            {
                float x = 0.f;
                if (tid < 256) {
                    x = hs[tid] + b2[li * DM + tid];
                    const float* fpb = f2part + (size_t)b * GROUP * DM + tid;
#pragma unroll
                    for (int mm = 0; mm < GROUP; ++mm)
                        x += __hip_atomic_load(&fpb[mm * DM], __ATOMIC_RELAXED,
                                               __HIP_MEMORY_SCOPE_AGENT);
                }
                float s = x, s2 = x * x;
#pragma unroll
                for (int o = 32; o > 0; o >>= 1) { s += __shfl_xor(s, o); s2 += __shfl_xor(s2, o); }
                if ((tid & 63) == 0) { red[wid] = s; red2[wid] = s2; }
                __syncthreads();
                if (tid < 256) {
                    float S = red[0] + red[1] + red[2] + red[3];
                    float S2 = red2[0] + red2[1] + red2[2] + red2[3];
                    float mu = S * (1.f / 256.f);
                    float var = S2 * (1.f / 256.f) - mu * mu;
                    float rr = rsqrtf(var + 1e-5f);
                    hs[tid] = (x - mu) * rr * ln2g[li * DM + tid] + ln2b[li * DM + tid];
                }
                __syncthreads();
            }
        }
        // ---- final projection (redundant) -> next pred ----
        {
            float v = (tid < 256) ? hs[tid] * fw[tid] : 0.f;
#pragma unroll
            for (int o = 32; o > 0; o >>= 1) v += __shfl_xor(v, o);
            if ((tid & 63) == 0) red[wid] = v;
            __syncthreads();
            pred = red[0] + red[1] + red[2] + red[3] + fb[0];
            if (m == 0 && tid == 0)
                out[((size_t)b * TT + p + 1) * DIN] = pred;
        }
    }
}

extern "C" void kernel_launch(void* const* d_in, const int* in_sizes, int n_in,
                              void* d_out, int out_size, void* d_ws, size_t ws_size,
                              hipStream_t stream) {
    const float* X     = (const float*)d_in[0];
    const float* emb_w = (const float*)d_in[1];
    const float* emb_b = (const float*)d_in[2];
    const float* Wq    = (const float*)d_in[3];
    const float* bq    = (const float*)d_in[4];
    const float* Wk    = (const float*)d_in[5];
    const float* bk    = (const float*)d_in[6];
    const float* Wv    = (const float*)d_in[7];
    const float* bv    = (const float*)d_in[8];
    const float* Wo    = (const float*)d_in[9];
    const float* bo    = (const float*)d_in[10];
    const float* ln1g  = (const float*)d_in[11];
    const float* ln1b  = (const float*)d_in[12];
    const float* W1    = (const float*)d_in[13];
    const float* b1    = (const float*)d_in[14];
    const float* W2    = (const float*)d_in[15];
    const float* b2    = (const float*)d_in[16];
    const float* ln2g  = (const float*)d_in[17];
    const float* ln2b  = (const float*)d_in[18];
    const float* fw    = (const float*)d_in[19];
    const float* fb    = (const float*)d_in[20];
    float* out = (float*)d_out;

    // workspace layout (floats)
    float* ws = (float*)d_ws;
    const size_t HROWS = (size_t)PRE_ROWS * DM;
    float* h   = ws;
    float* qa  = ws + HROWS;
    float* pre = ws + 2 * HROWS;
    float* ff  = ws + 3 * HROWS;
    float* Kc  = ws + 3 * HROWS + (size_t)PRE_ROWS * DFF;
    float* Vc  = Kc + (size_t)NLAY * BN * TT * DM;
    const size_t LSL = (size_t)BN * TT * DM;
    unsigned* qp8 = (unsigned*)(Vc + (size_t)NLAY * BN * TT * DM);
    unsigned* kp8 = qp8 + 65536;
    unsigned* vp8 = kp8 + 65536;
    unsigned* op8 = vp8 + 65536;
    unsigned* w18 = op8 + 65536;
    unsigned* w28 = w18 + 262144;
    float* opart  = (float*)(w28 + 262144);            // 64 x 8 x 256
    float* f2part = opart + BN * GROUP * DM;
    unsigned* ctrs = (unsigned*)(f2part + BN * GROUP * DM);
    half8* qf  = (half8*)(ctrs + BN * CTR_STRIDE);
    half8* kf  = qf + 4 * 8192;
    half8* vf  = kf + 4 * 8192;
    half8* of  = vf + 4 * 8192;
    half8* w1f = of + 4 * 8192;
    half8* w2f = w1f + 4 * 32768;

    // pack fp8 (decode) — layer via blockIdx.z
    pack8_k<<<dim3(1, 64, 4),  256, 0, stream>>>(Wq, qp8, DM, (size_t)DM * DM, 16384);
    pack8_k<<<dim3(1, 64, 4),  256, 0, stream>>>(Wk, kp8, DM, (size_t)DM * DM, 16384);
    pack8_k<<<dim3(1, 64, 4),  256, 0, stream>>>(Wv, vp8, DM, (size_t)DM * DM, 16384);
    pack8_k<<<dim3(1, 64, 4),  256, 0, stream>>>(Wo, op8, DM, (size_t)DM * DM, 16384);
    pack8_k<<<dim3(4, 64, 4),  256, 0, stream>>>(W1, w18, DFF, (size_t)DM * DFF, 65536);
    pack8_k<<<dim3(1, 256, 4), 256, 0, stream>>>(W2, w28, DM, (size_t)DFF * DM, 65536);
    // pack f16 MFMA fragments (prefill) — layer via blockIdx.y
    packBf_k<<<dim3(32, 4),  256, 0, stream>>>(Wq, qf,  DM,  DM,  (size_t)DM * DM,  8192);
    packBf_k<<<dim3(32, 4),  256, 0, stream>>>(Wk, kf,  DM,  DM,  (size_t)DM * DM,  8192);
    packBf_k<<<dim3(32, 4),  256, 0, stream>>>(Wv, vf,  DM,  DM,  (size_t)DM * DM,  8192);
    packBf_k<<<dim3(32, 4),  256, 0, stream>>>(Wo, of,  DM,  DM,  (size_t)DM * DM,  8192);
    packBf_k<<<dim3(128, 4), 256, 0, stream>>>(W1, w1f, DFF, DM,  (size_t)DM * DFF, 32768);
    packBf_k<<<dim3(128, 4), 256, 0, stream>>>(W2, w2f, DM,  DFF, (size_t)DFF * DM, 32768);
    init_ctr_k<<<(BN * CTR_STRIDE + 255) / 256, 256, 0, stream>>>(ctrs);

    copy_out_k<<<(BN * TT * DIN + 255) / 256, 256, 0, stream>>>(X, out, BN * TT * DIN);
    embed_k<<<PRE_ROWS, 256, 0, stream>>>(X, emb_w, emb_b, h);

    for (int li = 0; li < NLAY; ++li) {
        mgemm_qkv_k<<<dim3(12, 160), 256, 0, stream>>>(h,
                qf + (size_t)li * 8192, kf + (size_t)li * 8192, vf + (size_t)li * 8192,
                bq + li * DM, bk + li * DM, bv + li * DM,
                qa, Kc + li * LSL, Vc + li * LSL);
        attn_k<<<dim3(ILEN, BN), 256, 0, stream>>>(qa, Kc + li * LSL, Vc + li * LSL, qa);
        mgemm_k<<<dim3(4, 160), 256, 0, stream>>>(qa, of + (size_t)li * 8192,
                bo + li * DM, h, pre, DM, DM, 2, 0);
        ln4_k<<<PRE_ROWS / 4, 256, 0, stream>>>(pre, ln1g + li * DM, ln1b + li * DM, h);
        mgemm_k<<<dim3(16, 160), 256, 0, stream>>>(h, w1f + (size_t)li * 32768,
                b1 + li * DFF, nullptr, ff, DFF, DM, 1, 0);
        mgemm_k<<<dim3(4, 160), 256, 0, stream>>>(ff, w2f + (size_t)li * 32768,
                b2 + li * DM, h, pre, DM, DFF, 2, 0);
        ln4_k<<<PRE_ROWS / 4, 256, 0, stream>>>(pre, ln2g + li * DM, ln2b + li * DM, h);
    }
    final_k<<<BN, 256, 0, stream>>>(h, fw, fb, out);

    decode10_k<<<BN * GROUP, 1024, 0, stream>>>(X, emb_w, emb_b, bq, bk, bv, bo,
                                                ln1g, ln1b, b1, b2, ln2g, ln2b, fw, fb,
                                                Kc, Vc, qp8, kp8, vp8, op8, w18, w28,
                                                opart, f2part, ctrs, out);
}

// Round 13
// 2661.253 us; speedup vs baseline: 1.4814x; 1.4814x over previous
//
#include <hip/hip_runtime.h>
#include <hip/hip_bf16.h>

// Model dims
#define BN 64      // batch
#define TT 192     // total seq
#define ILEN 160   // input_len
#define DIN 8
#define DM 256
#define NH 8
#define DH 32
#define DFF 1024
#define NLAY 4
#define PRE_ROWS (BN * ILEN)   // 10240
#define SCALE 0.17677669529663687f  // 1/sqrt(32)
#define GROUP 4                // decode blocks per batch
#define CTR_STRIDE 64          // pad barrier counters to 256B each

typedef float f2v __attribute__((ext_vector_type(2)));
typedef _Float16 half8 __attribute__((ext_vector_type(8)));
typedef _Float16 h4v __attribute__((ext_vector_type(4)));
typedef float floatx4 __attribute__((ext_vector_type(4)));

#if defined(__has_builtin)
#if __has_builtin(__builtin_amdgcn_cvt_pk_f32_fp8) && __has_builtin(__builtin_amdgcn_cvt_pk_fp8_f32)
#define HW_FP8 1
#endif
#endif

// ---- software e4m3fn fallback (only used if builtins missing) ----
static __device__ inline float dec1_sw(unsigned b) {
    unsigned s = b >> 7, e = (b >> 3) & 15, mn = b & 7;
    float v;
    if (e == 0) v = (float)mn * 0.001953125f;
    else v = (8.0f + (float)mn) * exp2f((float)e - 10.0f);
    return s ? -v : v;
}
static __device__ inline unsigned enc1_sw(float x) {
    unsigned s = (x < 0.f) ? 0x80u : 0u;
    float ax = fabsf(x);
    if (ax > 448.f) ax = 448.f;
    if (ax < 0.0009765625f) return s;
    int e; frexpf(ax, &e);
    int E = e + 6;
    if (E <= 0) {
        int mn = (int)(ax * 512.f + 0.5f);
        if (mn > 7) return s | 0x08u;
        return s | (unsigned)mn;
    }
    if (E > 15) E = 15;
    int mn = (int)(ax * exp2f(10.f - (float)E) + 0.5f) - 8;
    if (mn > 7) { mn = 0; ++E; if (E > 15) { E = 15; mn = 7; } }
    if (mn < 0) mn = 0;
    return s | ((unsigned)E << 3) | (unsigned)mn;
}

static __device__ inline unsigned enc4(float a, float b, float c, float d) {
#ifdef HW_FP8
    int v = __builtin_amdgcn_cvt_pk_fp8_f32(a, b, 0, false);
    v = __builtin_amdgcn_cvt_pk_fp8_f32(c, d, v, true);
    return (unsigned)v;
#else
    return enc1_sw(a) | (enc1_sw(b) << 8) | (enc1_sw(c) << 16) | (enc1_sw(d) << 24);
#endif
}

static __device__ inline float dot4u(unsigned u, const float* h, float a) {
#ifdef HW_FP8
    f2v lo = __builtin_amdgcn_cvt_pk_f32_fp8((int)u, false);
    f2v hi = __builtin_amdgcn_cvt_pk_f32_fp8((int)u, true);
    a = fmaf(lo.x, h[0], a); a = fmaf(lo.y, h[1], a);
    a = fmaf(hi.x, h[2], a); a = fmaf(hi.y, h[3], a);
#else
    a = fmaf(dec1_sw(u & 255u), h[0], a);
    a = fmaf(dec1_sw((u >> 8) & 255u), h[1], a);
    a = fmaf(dec1_sw((u >> 16) & 255u), h[2], a);
    a = fmaf(dec1_sw((u >> 24) & 255u), h[3], a);
#endif
    return a;
}
static __device__ inline void dec4(unsigned u, float* o) {
#ifdef HW_FP8
    f2v lo = __builtin_amdgcn_cvt_pk_f32_fp8((int)u, false);
    f2v hi = __builtin_amdgcn_cvt_pk_f32_fp8((int)u, true);
    o[0] = lo.x; o[1] = lo.y; o[2] = hi.x; o[3] = hi.y;
#else
    o[0] = dec1_sw(u & 255u); o[1] = dec1_sw((u >> 8) & 255u);
    o[2] = dec1_sw((u >> 16) & 255u); o[3] = dec1_sw((u >> 24) & 255u);
#endif
}

// ---------------- copy whole_example -> out ----------------
__global__ void copy_out_k(const float* __restrict__ X, float* __restrict__ O, int n) {
    int i = blockIdx.x * blockDim.x + threadIdx.x;
    if (i < n) O[i] = X[i];
}

// ---------------- zero the (padded) group-barrier counters ----------------
__global__ void init_ctr_k(unsigned* __restrict__ ctr) {
    int i = blockIdx.x * 256 + threadIdx.x;
    if (i < BN * CTR_STRIDE) ctr[i] = 0u;
}

// ---------------- pack fp32 [K][N] -> fp8 dwords [K/4][N], x256; z = layer ----------------
__global__ __launch_bounds__(256) void pack8_k(const float* __restrict__ src0,
        unsigned* __restrict__ dst0, int N, size_t sstride, size_t dstride) {
    const float* src = src0 + blockIdx.z * sstride;
    unsigned* dst = dst0 + blockIdx.z * dstride;
    int o = blockIdx.x * 256 + threadIdx.x;
    int k4 = blockIdx.y;
    if (o < N) {
        float a = src[(size_t)(4 * k4) * N + o] * 256.f;
        float b = src[(size_t)(4 * k4 + 1) * N + o] * 256.f;
        float c = src[(size_t)(4 * k4 + 2) * N + o] * 256.f;
        float d = src[(size_t)(4 * k4 + 3) * N + o] * 256.f;
        dst[(size_t)k4 * N + o] = enc4(a, b, c, d);
    }
}

// ---------------- pack fp32 [K][N] -> f16 MFMA B-fragments (prefill); y = layer ----------------
__global__ __launch_bounds__(256) void packBf_k(const float* __restrict__ W,
        half8* __restrict__ dst, int N, int K, size_t wstride, size_t dstride) {
    const float* Wl = W + blockIdx.y * wstride;
    half8* dl = dst + blockIdx.y * dstride;
    int idx = blockIdx.x * 256 + threadIdx.x;
    int l = idx & 63;
    int f = idx >> 6;
    int nfr = N >> 4;
    if (f < (K >> 5) * nfr) {
        int ktg = f / nfr, ctg = f - ktg * nfr;
        int row = ktg * 32 + 8 * (l >> 4);
        int col = ctg * 16 + (l & 15);
        half8 v;
#pragma unroll
        for (int i = 0; i < 8; ++i)
            v[i] = (_Float16)Wl[(size_t)(row + i) * N + col];
        dl[(size_t)f * 64 + l] = v;
    }
}

// ---------------- embedding for prefill rows ----------------
__global__ __launch_bounds__(256) void embed_k(const float* __restrict__ X,
        const float* __restrict__ w, const float* __restrict__ bias,
        float* __restrict__ H) {
    int row = blockIdx.x;
    int b = row / ILEN, p = row % ILEN;
    int tid = threadIdx.x;
    const float* x = X + (size_t)(b * TT + p) * DIN;
    float acc = bias[tid];
#pragma unroll
    for (int r = 0; r < DIN; ++r) acc += x[r] * w[r * DM + tid];
    H[(size_t)row * DM + tid] = acc;
}

// ---- shared A-staging: 64 rows x 256 cols f32 -> f16 LDS, fully coalesced ----
static __device__ inline void stageA(const float* __restrict__ A, int row0, int K,
                                     int kc0, _Float16 (*As)[264], int tid) {
#pragma unroll
    for (int i = 0; i < 16; ++i) {
        int idx = i * 256 + tid;            // 0..4095
        int r = idx >> 6, c4 = (idx & 63) * 4;
        float4 v = *(const float4*)(A + (size_t)(row0 + r) * K + kc0 + c4);
        h4v hv = {(_Float16)v.x, (_Float16)v.y, (_Float16)v.z, (_Float16)v.w};
        *(h4v*)&As[r][c4] = hv;
    }
}

// ---------------- MFMA f16 GEMM: C = A@W + bias (+epilogue) ----------------
__global__ __launch_bounds__(256) void mgemm_k(
        const float* __restrict__ A, const half8* __restrict__ Bp,
        const float* __restrict__ bias, const float* __restrict__ R,
        float* __restrict__ C, int N, int K, int mode, int remap) {
    __shared__ _Float16 As[64][264];
    const int tid = threadIdx.x;
    const int lane = tid & 63;
    const int w16 = (tid >> 6) * 16;
    const int bx = blockIdx.x;
    const int row0 = blockIdx.y * 64;
    const int nfr = N >> 4;
    const int ctg0 = bx << 2;

    floatx4 acc[4] = {};
    for (int kc0 = 0; kc0 < K; kc0 += 256) {
        stageA(A, row0, K, kc0, As, tid);
        __syncthreads();
#pragma unroll
        for (int kt = 0; kt < 8; ++kt) {
            half8 af = *(const half8*)&As[w16 + (lane & 15)][kt * 32 + 8 * (lane >> 4)];
            size_t ktg = (kc0 >> 5) + kt;
#pragma unroll
            for (int ct = 0; ct < 4; ++ct) {
                half8 bf = Bp[(ktg * nfr + ctg0 + ct) * 64 + lane];
                acc[ct] = __builtin_amdgcn_mfma_f32_16x16x32_f16(af, bf, acc[ct], 0, 0, 0);
            }
        }
        __syncthreads();
    }
    int rbase = row0 + w16 + 4 * (lane >> 4);
#pragma unroll
    for (int ct = 0; ct < 4; ++ct) {
        int col = (bx << 6) + (ct << 4) + (lane & 15);
        float bb = bias[col];
#pragma unroll
        for (int i = 0; i < 4; ++i) {
            int row = rbase + i;
            float v = acc[ct][i] + bb;
            if (mode == 1) v = fmaxf(v, 0.f);
            if (mode == 2) v += R[(size_t)row * N + col];
            int orow = remap ? (row / ILEN) * TT + (row % ILEN) : row;
            C[(size_t)orow * N + col] = v;
        }
    }
}

// ---------------- fused QKV MFMA GEMM (K=256, N=256 each; mat by blockIdx.x>>2) ----------------
__global__ __launch_bounds__(256) void mgemm_qkv_k(
        const float* __restrict__ A,
        const half8* __restrict__ qf, const half8* __restrict__ kf,
        const half8* __restrict__ vf,
        const float* __restrict__ bq, const float* __restrict__ bk,
        const float* __restrict__ bv,
        float* __restrict__ qa, float* __restrict__ Kc, float* __restrict__ Vc) {
    __shared__ _Float16 As[64][264];
    const int tid = threadIdx.x;
    const int lane = tid & 63;
    const int w16 = (tid >> 6) * 16;
    const int mat = blockIdx.x >> 2;
    const int bx = blockIdx.x & 3;
    const int row0 = blockIdx.y * 64;
    const int ctg0 = bx << 2;
    const half8* Bp = (mat == 0) ? qf : (mat == 1) ? kf : vf;
    const float* bias = (mat == 0) ? bq : (mat == 1) ? bk : bv;
    float* C = (mat == 0) ? qa : (mat == 1) ? Kc : Vc;

    floatx4 acc[4] = {};
    stageA(A, row0, DM, 0, As, tid);
    __syncthreads();
#pragma unroll
    for (int kt = 0; kt < 8; ++kt) {
        half8 af = *(const half8*)&As[w16 + (lane & 15)][kt * 32 + 8 * (lane >> 4)];
#pragma unroll
        for (int ct = 0; ct < 4; ++ct) {
            half8 bf = Bp[((size_t)kt * 16 + ctg0 + ct) * 64 + lane];
            acc[ct] = __builtin_amdgcn_mfma_f32_16x16x32_f16(af, bf, acc[ct], 0, 0, 0);
        }
    }
    int rbase = row0 + w16 + 4 * (lane >> 4);
#pragma unroll
    for (int ct = 0; ct < 4; ++ct) {
        int col = (bx << 6) + (ct << 4) + (lane & 15);
        float bb = bias[col];
#pragma unroll
        for (int i = 0; i < 4; ++i) {
            int row = rbase + i;
            float v = acc[ct][i] + bb;
            int orow = mat ? (row / ILEN) * TT + (row % ILEN) : row;
            C[(size_t)orow * DM + col] = v;
        }
    }
}

// ---------------- prefill attention (coalesced K-dot) ----------------
__global__ __launch_bounds__(256) void attn_k(
        const float* __restrict__ Q, const float* __restrict__ Kc,
        const float* __restrict__ Vc, float* __restrict__ O) {
    int qp = blockIdx.x;
    int b = blockIdx.y;
    int tid = threadIdx.x;
    int hh = tid >> 5, l = tid & 31;
    int jj = l >> 3, dd = l & 7;      // 4 j-rows x 8 d-quads per 32-lane group
    __shared__ float qs[DM];
    __shared__ float sc[NH][TT];
    int qrow = b * ILEN + qp;
    qs[tid] = Q[(size_t)qrow * DM + tid] * SCALE;
    __syncthreads();
    const float* Kb = Kc + (size_t)b * TT * DM;
    const float* Vb = Vc + (size_t)b * TT * DM;
    float q0 = qs[hh * DH + dd * 4], q1 = qs[hh * DH + dd * 4 + 1];
    float q2 = qs[hh * DH + dd * 4 + 2], q3 = qs[hh * DH + dd * 4 + 3];
    float mx = -1e30f;
    for (int jb = 0; jb <= qp; jb += 4) {
        int j = jb + jj;
        bool ok = (j <= qp);
        int jc = ok ? j : qp;
        float4 kv = *(const float4*)(Kb + (size_t)jc * DM + hh * DH + dd * 4);
        float pd = kv.x * q0 + kv.y * q1 + kv.z * q2 + kv.w * q3;
        pd += __shfl_xor(pd, 1); pd += __shfl_xor(pd, 2); pd += __shfl_xor(pd, 4);
        if (ok) {
            if (dd == 0) sc[hh][j] = pd;
            mx = fmaxf(mx, pd);
        }
    }
#pragma unroll
    for (int o = 16; o > 0; o >>= 1) mx = fmaxf(mx, __shfl_xor(mx, o, 32));
    float sum = 0.f;
    for (int j = l; j <= qp; j += 32) {
        float p = __expf(sc[hh][j] - mx);
        sc[hh][j] = p;
        sum += p;
    }
#pragma unroll
    for (int o = 16; o > 0; o >>= 1) sum += __shfl_xor(sum, o, 32);
    float inv = 1.f / sum;
    float acc = 0.f;
    for (int j = 0; j <= qp; ++j)
        acc += sc[hh][j] * Vb[(size_t)j * DM + hh * DH + l];
    O[(size_t)qrow * DM + hh * DH + l] = acc * inv;
}

// ---------------- layernorm: one wave per row, 4 rows/block ----------------
__global__ __launch_bounds__(256) void ln4_k(const float* __restrict__ Xp,
        const float* __restrict__ g, const float* __restrict__ be,
        float* __restrict__ Y) {
    int row = blockIdx.x * 4 + (threadIdx.x >> 6);
    int l = threadIdx.x & 63;
    float4 x = *(const float4*)(Xp + (size_t)row * DM + 4 * l);
    float s = x.x + x.y + x.z + x.w;
    float s2 = x.x * x.x + x.y * x.y + x.z * x.z + x.w * x.w;
#pragma unroll
    for (int o = 32; o > 0; o >>= 1) { s += __shfl_xor(s, o); s2 += __shfl_xor(s2, o); }
    float mu = s * (1.f / 256.f);
    float var = s2 * (1.f / 256.f) - mu * mu;
    float rr = rsqrtf(var + 1e-5f);
    float4 gv = *(const float4*)(g + 4 * l);
    float4 bv = *(const float4*)(be + 4 * l);
    float4 o;
    o.x = (x.x - mu) * rr * gv.x + bv.x;
    o.y = (x.y - mu) * rr * gv.y + bv.y;
    o.z = (x.z - mu) * rr * gv.z + bv.z;
    o.w = (x.w - mu) * rr * gv.w + bv.w;
    *(float4*)(Y + (size_t)row * DM + 4 * l) = o;
}

// ---------------- final projection at position 159 -> pred0 ----------------
__global__ __launch_bounds__(256) void final_k(const float* __restrict__ H,
        const float* __restrict__ fw, const float* __restrict__ fb,
        float* __restrict__ out) {
    int b = blockIdx.x;
    int tid = threadIdx.x;
    float v = H[(size_t)(b * ILEN + ILEN - 1) * DM + tid] * fw[tid];
#pragma unroll
    for (int o = 32; o > 0; o >>= 1) v += __shfl_xor(v, o);
    __shared__ float red[4];
    if ((tid & 63) == 0) red[tid >> 6] = v;
    __syncthreads();
    if (tid == 0)
        out[((size_t)b * TT + ILEN) * DIN] = red[0] + red[1] + red[2] + red[3] + fb[0];
}

// ================= decode v7 (proven best: 1527-1553 us) ========
__device__ inline void gbar(unsigned* __restrict__ c, unsigned target, int tid) {
    __syncthreads();
    if (tid == 0) {
        __hip_atomic_fetch_add(c, 1u, __ATOMIC_RELAXED, __HIP_MEMORY_SCOPE_AGENT);
        int guard = 0;
        while (__hip_atomic_load(c, __ATOMIC_RELAXED, __HIP_MEMORY_SCOPE_AGENT) < target) {
            __builtin_amdgcn_s_sleep(1);
            if (++guard > (1 << 27)) break;
        }
    }
    __syncthreads();
}

#define KSTRIDE 20   // dwords/row, 16B-aligned for uint4 reads
#define VSTRIDE 17   // dwords/row, odd -> banks spread across j

__global__ __launch_bounds__(1024, 1) void decode7_k(
        const float* __restrict__ X,
        const float* __restrict__ emb_w, const float* __restrict__ emb_b,
        const float* __restrict__ bq, const float* __restrict__ bk,
        const float* __restrict__ bv, const float* __restrict__ bo,
        const float* __restrict__ ln1g, const float* __restrict__ ln1b,
        const float* __restrict__ b1, const float* __restrict__ b2,
        const float* __restrict__ ln2g, const float* __restrict__ ln2b,
        const float* __restrict__ fw, const float* __restrict__ fb,
        const float* __restrict__ Kc, const float* __restrict__ Vc,
        const unsigned* __restrict__ qp8, const unsigned* __restrict__ kp8,
        const unsigned* __restrict__ vp8, const unsigned* __restrict__ op8,
        const unsigned* __restrict__ w18, const unsigned* __restrict__ w28,
        float* __restrict__ opart, float* __restrict__ f2part,
        unsigned* __restrict__ ctrs,
        float* __restrict__ out) {
    const int bid = blockIdx.x;
    const int b = bid & 63;
    const int m = bid >> 6;
    const int tid = threadIdx.x;
    const int wid = tid >> 6;
    unsigned* ctr = ctrs + b * CTR_STRIDE;
    unsigned bt = 0;

    __shared__ unsigned Kl[NLAY * 192 * KSTRIDE];   // 61.4 KB
    __shared__ unsigned Vl[NLAY * 192 * VSTRIDE];   // 52.2 KB
    __shared__ float hs[256];
    __shared__ float qs[64];
    __shared__ float as_[64];
    __shared__ float sc[2][192];
    __shared__ float scr[2176];        // PV partials padded to 33/row
    __shared__ float tmp[256];
    __shared__ float ffs[256];
    __shared__ float red[16], red2[16];

    for (int it = 0; it < 10; ++it) {
        int idx = it * 1024 + tid;
        int d4 = idx & 15;
        int r640 = idx >> 4;
        int l = r640 / 160;
        int row = r640 - l * 160;
        size_t base = ((size_t)(l * BN + b) * TT + row) * DM + m * 64 + d4 * 4;
        float4 kf = *(const float4*)(Kc + base);
        float4 vf = *(const float4*)(Vc + base);
        Kl[(l * 192 + row) * KSTRIDE + d4] =
            enc4(kf.x * 64.f, kf.y * 64.f, kf.z * 64.f, kf.w * 64.f);
        Vl[(l * 192 + row) * VSTRIDE + d4] =
            enc4(vf.x * 64.f, vf.y * 64.f, vf.z * 64.f, vf.w * 64.f);
    }
    float pred = out[((size_t)b * TT + ILEN) * DIN];
    __syncthreads();

    for (int t = 0; t < TT - ILEN - 1; ++t) {
        const int p = ILEN + t;
        __syncthreads();
        if (tid < 256) {
            float a = emb_b[tid];
#pragma unroll
            for (int r = 0; r < DIN; ++r) {
                float xr = (r == 0) ? pred : X[((size_t)b * TT + p) * DIN + r];
                a += xr * emb_w[r * DM + tid];
            }
            hs[tid] = a;
        }
        __syncthreads();

        for (int li = 0; li < NLAY; ++li) {
            const unsigned* wq8 = qp8 + (size_t)li * 16384;
            const unsigned* wk8 = kp8 + (size_t)li * 16384;
            const unsigned* wv8 = vp8 + (size_t)li * 16384;
            const unsigned* wo8 = op8 + (size_t)li * 16384;
            const unsigned* w18l = w18 + (size_t)li * 65536;
            const unsigned* w28l = w28 + (size_t)li * 65536;

            if (tid < 768) {
                int mat = tid >> 8, o = tid & 63, kc = (tid >> 6) & 3;
                int og = m * 64 + o;
                const unsigned* w = (mat == 0) ? wq8 : (mat == 1) ? wk8 : wv8;
                const unsigned* wp = w + (size_t)(kc * 16) * 256 + og;
                const float* hq = hs + kc * 64;
                float a = 0.f;
#pragma unroll
                for (int i = 0; i < 16; ++i)
                    a = dot4u(wp[(size_t)i * 256], hq + i * 4, a);
                scr[mat * 256 + kc * 64 + o] = a;
            }
            __syncthreads();
            if (tid < 192) {
                int mat = tid >> 6, o = tid & 63, og = m * 64 + o;
                float v = (scr[mat * 256 + o] + scr[mat * 256 + 64 + o] +
                           scr[mat * 256 + 128 + o] + scr[mat * 256 + 192 + o]) * (1.f / 256.f);
                if (mat == 0) qs[o] = (v + bq[li * DM + og]) * (SCALE / 64.f);
                else if (mat == 1) tmp[o] = (v + bk[li * DM + og]) * 64.f;
                else tmp[64 + o] = (v + bv[li * DM + og]) * 64.f;
            }
            __syncthreads();
            if (tid < 32) {
                int i = tid & 15;
                if (tid < 16)
                    Kl[(li * 192 + p) * KSTRIDE + i] =
                        enc4(tmp[4 * i], tmp[4 * i + 1], tmp[4 * i + 2], tmp[4 * i + 3]);
                else
                    Vl[(li * 192 + p) * VSTRIDE + i] =
                        enc4(tmp[64 + 4 * i], tmp[64 + 4 * i + 1],
                             tmp[64 + 4 * i + 2], tmp[64 + 4 * i + 3]);
            }
            __syncthreads();

            {
                const int hl = tid >> 9;
                const int u = tid & 511;
                float mval = -1e30f;
                if (u <= p) {
                    const unsigned* kr = Kl + (li * 192 + u) * KSTRIDE + hl * 8;
                    uint4 k0 = *(const uint4*)kr;
                    uint4 k1 = *(const uint4*)(kr + 4);
                    const float* qq = qs + hl * 32;
                    float d = 0.f;
                    d = dot4u(k0.x, qq + 0, d);  d = dot4u(k0.y, qq + 4, d);
                    d = dot4u(k0.z, qq + 8, d);  d = dot4u(k0.w, qq + 12, d);
                    d = dot4u(k1.x, qq + 16, d); d = dot4u(k1.y, qq + 20, d);
                    d = dot4u(k1.z, qq + 24, d); d = dot4u(k1.w, qq + 28, d);
                    sc[hl][u] = d;
                    mval = d;
                }
#pragma unroll
                for (int o = 32; o > 0; o >>= 1) mval = fmaxf(mval, __shfl_xor(mval, o));
                if ((tid & 63) == 0) red[wid] = mval;
                __syncthreads();
                float mx = red[hl * 8];
#pragma unroll
                for (int r = 1; r < 8; ++r) mx = fmaxf(mx, red[hl * 8 + r]);
                float sval = 0.f;
                if (u <= p) {
                    float e = __expf(sc[hl][u] - mx);
                    sc[hl][u] = e;
                    sval = e;
                }
#pragma unroll
                for (int o = 32; o > 0; o >>= 1) sval += __shfl_xor(sval, o);
                if ((tid & 63) == 0) red2[wid] = sval;
                __syncthreads();
                if (u < 256) {
                    int d4 = u & 7, jc = u >> 3;
                    float a0 = 0.f, a1 = 0.f, a2 = 0.f, a3 = 0.f;
#pragma unroll
                    for (int it2 = 0; it2 < 6; ++it2) {
                        int j = jc + 32 * it2;
                        if (j <= p) {
                            float pe = sc[hl][j];
                            float vv[4];
                            dec4(Vl[(li * 192 + j) * VSTRIDE + hl * 8 + d4], vv);
                            a0 = fmaf(pe, vv[0], a0); a1 = fmaf(pe, vv[1], a1);
                            a2 = fmaf(pe, vv[2], a2); a3 = fmaf(pe, vv[3], a3);
                        }
                    }
                    int ob = (hl * 8 + d4) * 4;
                    scr[(ob + 0) * 33 + jc] = a0; scr[(ob + 1) * 33 + jc] = a1;
                    scr[(ob + 2) * 33 + jc] = a2; scr[(ob + 3) * 33 + jc] = a3;
                }
            }
            __syncthreads();
            if (tid < 256) {
                int o = tid & 63, q4 = tid >> 6;
                float a = 0.f;
#pragma unroll
                for (int r = 0; r < 8; ++r) a += scr[o * 33 + q4 * 8 + r];
                tmp[q4 * 64 + o] = a;
            }
            __syncthreads();
            if (tid < 64) {
                int hl = tid >> 5;
                float s = red2[hl * 8];
#pragma unroll
                for (int r = 1; r < 8; ++r) s += red2[hl * 8 + r];
                float inv = 1.f / (64.f * s);
                as_[tid] = (tmp[tid] + tmp[64 + tid] + tmp[128 + tid] + tmp[192 + tid]) * inv;
            }
            __syncthreads();

            {
                int o = tid & 255, kc = tid >> 8;
                const unsigned* wp = wo8 + (size_t)(m * 16 + kc * 4) * 256 + o;
                const float* aq = as_ + kc * 16;
                float a = 0.f;
#pragma unroll
                for (int i = 0; i < 4; ++i)
                    a = dot4u(wp[(size_t)i * 256], aq + i * 4, a);
                scr[kc * 256 + o] = a;
            }
            __syncthreads();
            if (tid < 256)
                __hip_atomic_store(&opart[((size_t)b * GROUP + m) * DM + tid],
                    (scr[tid] + scr[256 + tid] + scr[512 + tid] + scr[768 + tid]) * (1.f / 256.f),
                    __ATOMIC_RELAXED, __HIP_MEMORY_SCOPE_AGENT);
            bt += GROUP; gbar(ctr, bt, tid);

            {
                float x = 0.f;
                if (tid < 256) {
                    x = hs[tid] + bo[li * DM + tid];
                    const float* opb = opart + (size_t)b * GROUP * DM + tid;
#pragma unroll
                    for (int mm = 0; mm < GROUP; ++mm)
                        x += __hip_atomic_load(&opb[mm * DM], __ATOMIC_RELAXED,
                                               __HIP_MEMORY_SCOPE_AGENT);
                }
                float s = x, s2 = x * x;
#pragma unroll
                for (int o = 32; o > 0; o >>= 1) { s += __shfl_xor(s, o); s2 += __shfl_xor(s2, o); }
                if ((tid & 63) == 0) { red[wid] = s; red2[wid] = s2; }
                __syncthreads();
                if (tid < 256) {
                    float S = red[0] + red[1] + red[2] + red[3];
                    float S2 = red2[0] + red2[1] + red2[2] + red2[3];
                    float mu = S * (1.f / 256.f);
                    float var = S2 * (1.f / 256.f) - mu * mu;
                    float rr = rsqrtf(var + 1e-5f);
                    hs[tid] = (x - mu) * rr * ln1g[li * DM + tid] + ln1b[li * DM + tid];
                }
                __syncthreads();
            }
            {
                int o = tid & 255, kc = tid >> 8;
                int og = m * 256 + o;
                const unsigned* wp = w18l + (size_t)(kc * 16) * 1024 + og;
                const float* hq = hs + kc * 64;
                float a = 0.f;
#pragma unroll
                for (int i = 0; i < 16; ++i)
                    a = dot4u(wp[(size_t)i * 1024], hq + i * 4, a);
                scr[kc * 256 + o] = a;
            }
            __syncthreads();
            if (tid < 256)
                ffs[tid] = fmaxf((scr[tid] + scr[256 + tid] + scr[512 + tid] + scr[768 + tid])
                                     * (1.f / 256.f) + b1[li * DFF + m * 256 + tid], 0.f);
            __syncthreads();
            {
                int o = tid & 255, kc = tid >> 8;
                const unsigned* wp = w28l + (size_t)(m * 64 + kc * 16) * 256 + o;
                const float* hq = ffs + kc * 64;
                float a = 0.f;
#pragma unroll
                for (int i = 0; i < 16; ++i)
                    a = dot4u(wp[(size_t)i * 256], hq + i * 4, a);
                scr[kc * 256 + o] = a;
            }
            __syncthreads();
            if (tid < 256)
                __hip_atomic_store(&f2part[((size_t)b * GROUP + m) * DM + tid],
                    (scr[tid] + scr[256 + tid] + scr[512 + tid] + scr[768 + tid]) * (1.f / 256.f),
                    __ATOMIC_RELAXED, __HIP_MEMORY_SCOPE_AGENT);
            bt += GROUP; gbar(ctr, bt, tid);

            {
                float x = 0.f;
                if (tid < 256) {
                    x = hs[tid] + b2[li * DM + tid];
                    const float* fpb = f2part + (size_t)b * GROUP * DM + tid;
#pragma unroll
                    for (int mm = 0; mm < GROUP; ++mm)
                        x += __hip_atomic_load(&fpb[mm * DM], __ATOMIC_RELAXED,
                                               __HIP_MEMORY_SCOPE_AGENT);
                }
                float s = x, s2 = x * x;
#pragma unroll
                for (int o = 32; o > 0; o >>= 1) { s += __shfl_xor(s, o); s2 += __shfl_xor(s2, o); }
                if ((tid & 63) == 0) { red[wid] = s; red2[wid] = s2; }
                __syncthreads();
                if (tid < 256) {
                    float S = red[0] + red[1] + red[2] + red[3];
                    float S2 = red2[0] + red2[1] + red2[2] + red2[3];
                    float mu = S * (1.f / 256.f);
                    float var = S2 * (1.f / 256.f) - mu * mu;
                    float rr = rsqrtf(var + 1e-5f);
                    hs[tid] = (x - mu) * rr * ln2g[li * DM + tid] + ln2b[li * DM + tid];
                }
                __syncthreads();
            }
        }
        {
            float v = (tid < 256) ? hs[tid] * fw[tid] : 0.f;
#pragma unroll
            for (int o = 32; o > 0; o >>= 1) v += __shfl_xor(v, o);
            if ((tid & 63) == 0) red[wid] = v;
            __syncthreads();
            pred = red[0] + red[1] + red[2] + red[3] + fb[0];
            if (m == 0 && tid == 0)
                out[((size_t)b * TT + p + 1) * DIN] = pred;
        }
    }
}

extern "C" void kernel_launch(void* const* d_in, const int* in_sizes, int n_in,
                              void* d_out, int out_size, void* d_ws, size_t ws_size,
                              hipStream_t stream) {
    const float* X     = (const float*)d_in[0];
    const float* emb_w = (const float*)d_in[1];
    const float* emb_b = (const float*)d_in[2];
    const float* Wq    = (const float*)d_in[3];
    const float* bq    = (const float*)d_in[4];
    const float* Wk    = (const float*)d_in[5];
    const float* bk    = (const float*)d_in[6];
    const float* Wv    = (const float*)d_in[7];
    const float* bv    = (const float*)d_in[8];
    const float* Wo    = (const float*)d_in[9];
    const float* bo    = (const float*)d_in[10];
    const float* ln1g  = (const float*)d_in[11];
    const float* ln1b  = (const float*)d_in[12];
    const float* W1    = (const float*)d_in[13];
    const float* b1    = (const float*)d_in[14];
    const float* W2    = (const float*)d_in[15];
    const float* b2    = (const float*)d_in[16];
    const float* ln2g  = (const float*)d_in[17];
    const float* ln2b  = (const float*)d_in[18];
    const float* fw    = (const float*)d_in[19];
    const float* fb    = (const float*)d_in[20];
    float* out = (float*)d_out;

    // workspace layout (floats)
    float* ws = (float*)d_ws;
    const size_t HROWS = (size_t)PRE_ROWS * DM;
    float* h   = ws;
    float* qa  = ws + HROWS;
    float* pre = ws + 2 * HROWS;
    float* ff  = ws + 3 * HROWS;
    float* Kc  = ws + 3 * HROWS + (size_t)PRE_ROWS * DFF;
    float* Vc  = Kc + (size_t)NLAY * BN * TT * DM;
    const size_t LSL = (size_t)BN * TT * DM;
    unsigned* qp8 = (unsigned*)(Vc + (size_t)NLAY * BN * TT * DM);
    unsigned* kp8 = qp8 + 65536;
    unsigned* vp8 = kp8 + 65536;
    unsigned* op8 = vp8 + 65536;
    unsigned* w18 = op8 + 65536;
    unsigned* w28 = w18 + 262144;
    float* opart  = (float*)(w28 + 262144);
    float* f2part = opart + BN * GROUP * DM;
    unsigned* ctrs = (unsigned*)(f2part + BN * GROUP * DM);
    half8* qf  = (half8*)(ctrs + BN * CTR_STRIDE);
    half8* kf  = qf + 4 * 8192;
    half8* vf  = kf + 4 * 8192;
    half8* of  = vf + 4 * 8192;
    half8* w1f = of + 4 * 8192;
    half8* w2f = w1f + 4 * 32768;

    // pack fp8 (decode) — layer via blockIdx.z
    pack8_k<<<dim3(1, 64, 4),  256, 0, stream>>>(Wq, qp8, DM, (size_t)DM * DM, 16384);
    pack8_k<<<dim3(1, 64, 4),  256, 0, stream>>>(Wk, kp8, DM, (size_t)DM * DM, 16384);
    pack8_k<<<dim3(1, 64, 4),  256, 0, stream>>>(Wv, vp8, DM, (size_t)DM * DM, 16384);
    pack8_k<<<dim3(1, 64, 4),  256, 0, stream>>>(Wo, op8, DM, (size_t)DM * DM, 16384);
    pack8_k<<<dim3(4, 64, 4),  256, 0, stream>>>(W1, w18, DFF, (size_t)DM * DFF, 65536);
    pack8_k<<<dim3(1, 256, 4), 256, 0, stream>>>(W2, w28, DM, (size_t)DFF * DM, 65536);
    // pack f16 MFMA fragments (prefill) — layer via blockIdx.y
    packBf_k<<<dim3(32, 4),  256, 0, stream>>>(Wq, qf,  DM,  DM,  (size_t)DM * DM,  8192);
    packBf_k<<<dim3(32, 4),  256, 0, stream>>>(Wk, kf,  DM,  DM,  (size_t)DM * DM,  8192);
    packBf_k<<<dim3(32, 4),  256, 0, stream>>>(Wv, vf,  DM,  DM,  (size_t)DM * DM,  8192);
    packBf_k<<<dim3(32, 4),  256, 0, stream>>>(Wo, of,  DM,  DM,  (size_t)DM * DM,  8192);
    packBf_k<<<dim3(128, 4), 256, 0, stream>>>(W1, w1f, DFF, DM,  (size_t)DM * DFF, 32768);
    packBf_k<<<dim3(128, 4), 256, 0, stream>>>(W2, w2f, DM,  DFF, (size_t)DFF * DM, 32768);
    init_ctr_k<<<(BN * CTR_STRIDE + 255) / 256, 256, 0, stream>>>(ctrs);

    copy_out_k<<<(BN * TT * DIN + 255) / 256, 256, 0, stream>>>(X, out, BN * TT * DIN);
    embed_k<<<PRE_ROWS, 256, 0, stream>>>(X, emb_w, emb_b, h);

    for (int li = 0; li < NLAY; ++li) {
        mgemm_qkv_k<<<dim3(12, 160), 256, 0, stream>>>(h,
                qf + (size_t)li * 8192, kf + (size_t)li * 8192, vf + (size_t)li * 8192,
                bq + li * DM, bk + li * DM, bv + li * DM,
                qa, Kc + li * LSL, Vc + li * LSL);
        attn_k<<<dim3(ILEN, BN), 256, 0, stream>>>(qa, Kc + li * LSL, Vc + li * LSL, qa);
        mgemm_k<<<dim3(4, 160), 256, 0, stream>>>(qa, of + (size_t)li * 8192,
                bo + li * DM, h, pre, DM, DM, 2, 0);
        ln4_k<<<PRE_ROWS / 4, 256, 0, stream>>>(pre, ln1g + li * DM, ln1b + li * DM, h);
        mgemm_k<<<dim3(16, 160), 256, 0, stream>>>(h, w1f + (size_t)li * 32768,
                b1 + li * DFF, nullptr, ff, DFF, DM, 1, 0);
        mgemm_k<<<dim3(4, 160), 256, 0, stream>>>(ff, w2f + (size_t)li * 32768,
                b2 + li * DM, h, pre, DM, DFF, 2, 0);
        ln4_k<<<PRE_ROWS / 4, 256, 0, stream>>>(pre, ln2g + li * DM, ln2b + li * DM, h);
    }
    final_k<<<BN, 256, 0, stream>>>(h, fw, fb, out);

    decode7_k<<<BN * GROUP, 1024, 0, stream>>>(X, emb_w, emb_b, bq, bk, bv, bo,
                                               ln1g, ln1b, b1, b2, ln2g, ln2b, fw, fb,
                                               Kc, Vc, qp8, kp8, vp8, op8, w18, w28,
                                               opart, f2part, ctrs, out);
}